// Round 12
// baseline (252.184 us; speedup 1.0000x reference)
//
#include <hip/hip_runtime.h>

#define N_CONS 100000
#define N_VAR  200000
#define N_TOT  (N_CONS + N_VAR)
#define N_EDGE 2000000
#define EMB 64

#define VSH 10
#define NBV 196    // ceil(200000/1024)
#define CAPV 12288
#define CSH 9
#define NBC 196    // ceil(100000/512)
#define CAPC 12288
#define CAPAV (CAPV + 3 * 1024)  // padded adj capacity per var bucket
#define CAPAC (CAPC + 3 * 512)   // padded adj capacity per cons bucket
#define NB_VAR ((N_VAR + 63) / 64)    // 3125
#define NB_CONS ((N_CONS + 63) / 64)  // 1563
#define NB_SCAT 512

typedef unsigned short u16;
typedef __attribute__((ext_vector_type(8))) short bf16x8;
typedef __attribute__((ext_vector_type(4))) float f32x4;

// ---------------- bf16 helpers ----------------

__device__ __forceinline__ float b2f_lo(unsigned u) {
  union { unsigned i; float f; } c;
  c.i = u << 16;
  return c.f;
}
__device__ __forceinline__ float b2f_hi(unsigned u) {
  union { unsigned i; float f; } c;
  c.i = u & 0xFFFF0000u;
  return c.f;
}
__device__ __forceinline__ unsigned pack_bf2(float a, float b) {
  unsigned ua = __float_as_uint(a), ub = __float_as_uint(b);
  unsigned ra = (ua + 0x7FFFu + ((ua >> 16) & 1u)) >> 16;
  unsigned rb = (ub + 0x7FFFu + ((ub >> 16) & 1u)) >> 16;
  return ra | (rb << 16);
}
__device__ __forceinline__ u16 f2bf(float a) {
  unsigned ua = __float_as_uint(a);
  return (u16)((ua + 0x7FFFu + ((ua >> 16) & 1u)) >> 16);
}

// ---------------- fused front: bucket_scatter + embed(x2) + pad-row zero ----------------

__device__ __forceinline__ void scatter_body(
    int b, char* smem, const int* __restrict__ row, const int* __restrict__ col,
    int* __restrict__ gcurV, int* __restrict__ gcurC, int* __restrict__ pairV,
    int* __restrict__ pairC) {
  int* hV = (int*)smem;
  int* hC = hV + NBV;
  int tid = threadIdx.x;
  int chunk = (N_EDGE + NB_SCAT - 1) / NB_SCAT;
  int lo = b * chunk;
  int hi = min(N_EDGE, lo + chunk);
  for (int i = tid; i < NBV; i += 256) hV[i] = 0;
  for (int i = tid; i < NBC; i += 256) hC[i] = 0;
  __syncthreads();
  for (int e = lo + tid; e < hi; e += 256) {
    atomicAdd(&hV[col[e] >> VSH], 1);
    atomicAdd(&hC[row[e] >> CSH], 1);
  }
  __syncthreads();
  for (int i = tid; i < NBV; i += 256) {
    int c = hV[i];
    hV[i] = c ? (i * CAPV + atomicAdd(&gcurV[i], c)) : 0;
  }
  for (int i = tid; i < NBC; i += 256) {
    int c = hC[i];
    hC[i] = c ? (i * CAPC + atomicAdd(&gcurC[i], c)) : 0;
  }
  __syncthreads();
  for (int e = lo + tid; e < hi; e += 256) {
    int r = row[e], c = col[e];
    int p = atomicAdd(&hV[c >> VSH], 1);
    pairV[p] = (r << VSH) | (c & ((1 << VSH) - 1));
    int q = atomicAdd(&hC[r >> CSH], 1);
    pairC[q] = (c << CSH) | (r & ((1 << CSH) - 1));
  }
}

// Embedding: GEMM1 fp32 (K=F), GEMM2 on MFMA (K=64, bf16)
template <int F>
__device__ __forceinline__ void embed_body(
    int blk, char* smem, const float* __restrict__ x,
    const float* __restrict__ shift, const float* __restrict__ scale,
    const float* __restrict__ W1, const float* __restrict__ b1,
    const float* __restrict__ W2, const float* __restrict__ b2,
    const float* __restrict__ bi, const float* __restrict__ bW,
    u16* __restrict__ outbf, int n) {
  float* Xs = (float*)smem;                    // [F][68]
  float* W1s = Xs + F * 68;                    // [F][68]
  u16 (*Hs)[72] = (u16(*)[72])(W1s + F * 68);  // [64][72]
  u16 (*W2s)[72] = (u16(*)[72])((char*)Hs + 64 * 72 * 2);
  float* b1s = (float*)((char*)W2s + 64 * 72 * 2);
  float* b2s = b1s + 64;
  float* bWs = b2s + 64;
  float* bis = bWs + 64;
  int t = threadIdx.x;
  int v0 = blk * 64;

  int sn = t & 63;
  int kq = t >> 6;
  {
    unsigned pk[8];
#pragma unroll
    for (int i = 0; i < 8; ++i) {
      float w0 = W2[(size_t)(kq * 16 + 2 * i) * 64 + sn];
      float w1 = W2[(size_t)(kq * 16 + 2 * i + 1) * 64 + sn];
      pk[i] = pack_bf2(w0, w1);
    }
    *(uint4*)&W2s[sn][kq * 16] = make_uint4(pk[0], pk[1], pk[2], pk[3]);
    *(uint4*)&W2s[sn][kq * 16 + 8] = make_uint4(pk[4], pk[5], pk[6], pk[7]);
  }
  for (int i = t; i < F * 64; i += 256) {
    int k = i >> 6, j = i & 63;
    W1s[k * 68 + j] = W1[i] * scale[k];
  }
  if (t < 64) {
    float acc = b1[t];
#pragma unroll
    for (int k = 0; k < F; ++k) acc += shift[k] * scale[k] * W1[k * 64 + t];
    b1s[t] = acc;
    b2s[t] = b2[t];
    bWs[t] = bW ? bW[t] : 0.f;
    bis[t] = (bi && v0 + t < n) ? bi[v0 + t] : 0.f;
  }
  for (int i = t; i < 64 * F; i += 256) {
    int r = i / F, k = i - r * F;
    int v = v0 + r;
    Xs[k * 68 + r] = (v < n) ? x[(size_t)v * F + k] : 0.f;
  }
  __syncthreads();

  int jt = t & 15;
  int vt = t >> 4;
  float c[4][4] = {};
#pragma unroll
  for (int k = 0; k < F; ++k) {
    float4 xv = *(const float4*)&Xs[k * 68 + vt * 4];
    float4 wv = *(const float4*)&W1s[k * 68 + jt * 4];
    c[0][0] += xv.x * wv.x; c[0][1] += xv.x * wv.y; c[0][2] += xv.x * wv.z; c[0][3] += xv.x * wv.w;
    c[1][0] += xv.y * wv.x; c[1][1] += xv.y * wv.y; c[1][2] += xv.y * wv.z; c[1][3] += xv.y * wv.w;
    c[2][0] += xv.z * wv.x; c[2][1] += xv.z * wv.y; c[2][2] += xv.z * wv.z; c[2][3] += xv.z * wv.w;
    c[3][0] += xv.w * wv.x; c[3][1] += xv.w * wv.y; c[3][2] += xv.w * wv.z; c[3][3] += xv.w * wv.w;
  }
#pragma unroll
  for (int i = 0; i < 4; ++i) {
    float h0 = fmaxf(c[i][0] + b1s[jt * 4 + 0], 0.f);
    float h1 = fmaxf(c[i][1] + b1s[jt * 4 + 1], 0.f);
    float h2 = fmaxf(c[i][2] + b1s[jt * 4 + 2], 0.f);
    float h3 = fmaxf(c[i][3] + b1s[jt * 4 + 3], 0.f);
    *(uint2*)&Hs[vt * 4 + i][jt * 4] = make_uint2(pack_bf2(h0, h1), pack_bf2(h2, h3));
  }
  __syncthreads();

  int l = t & 63;
  int w = t >> 6;
  int m0 = w * 16;
  int rA = m0 + (l & 15);
  int koffA = (l >> 4) * 8;
  f32x4 acc[4] = {};
  {
    bf16x8 a0 = *(const bf16x8*)&Hs[rA][koffA];
    bf16x8 a1 = *(const bf16x8*)&Hs[rA][32 + koffA];
#pragma unroll
    for (int cb = 0; cb < 4; ++cb) {
      int nB = cb * 16 + (l & 15);
      bf16x8 b0 = *(const bf16x8*)&W2s[nB][koffA];
      bf16x8 bb1 = *(const bf16x8*)&W2s[nB][32 + koffA];
      acc[cb] = __builtin_amdgcn_mfma_f32_16x16x32_bf16(a0, b0, acc[cb], 0, 0, 0);
      acc[cb] = __builtin_amdgcn_mfma_f32_16x16x32_bf16(a1, bb1, acc[cb], 0, 0, 0);
    }
  }
#pragma unroll
  for (int cb = 0; cb < 4; ++cb) {
    int colc = cb * 16 + (l & 15);
    float bias = b2s[colc];
    float bwv = bWs[colc];
#pragma unroll
    for (int j = 0; j < 4; ++j) {
      int rowc = m0 + (l >> 4) * 4 + j;
      int v = v0 + rowc;
      if (v < n) {
        float val = fmaxf(acc[cb][j] + bias, 0.f) + bis[rowc] * bwv;
        outbf[(size_t)v * 64 + colc] = f2bf(val);
      }
    }
  }
}

#define FRONT_SMEM 29824

__global__ __launch_bounds__(256) void fused_front(
    const int* __restrict__ row, const int* __restrict__ col,
    int* __restrict__ gcurV, int* __restrict__ gcurC, int* __restrict__ pairV,
    int* __restrict__ pairC, const float* __restrict__ cons_x,
    const float* __restrict__ c_sh, const float* __restrict__ c_sc,
    const float* __restrict__ cW1, const float* __restrict__ cb1,
    const float* __restrict__ cW2, const float* __restrict__ cb2,
    const float* __restrict__ var_x, const float* __restrict__ v_sh,
    const float* __restrict__ v_sc, const float* __restrict__ vW1,
    const float* __restrict__ vb1, const float* __restrict__ vW2,
    const float* __restrict__ vb2, const float* __restrict__ bi,
    const float* __restrict__ bW, u16* __restrict__ consEbf,
    u16* __restrict__ varEbf, uint2* __restrict__ padrows0,
    uint2* __restrict__ padrows1, uint2* __restrict__ padrows2) {
  __shared__ __align__(16) char smem[FRONT_SMEM];
  int b = blockIdx.x;
  if (b < NB_SCAT) {
    scatter_body(b, smem, row, col, gcurV, gcurC, pairV, pairC);
  } else if (b < NB_SCAT + NB_CONS) {
    embed_body<5>(b - NB_SCAT, smem, cons_x, c_sh, c_sc, cW1, cb1, cW2, cb2,
                  nullptr, nullptr, consEbf, N_CONS);
  } else if (b < NB_SCAT + NB_CONS + NB_VAR) {
    embed_body<19>(b - NB_SCAT - NB_CONS, smem, var_x, v_sh, v_sc, vW1, vb1,
                   vW2, vb2, bi, bW, varEbf, N_VAR);
  } else {
    int t = threadIdx.x;
    if (t < 16) padrows0[t] = make_uint2(0u, 0u);
    else if (t < 32) padrows1[t - 16] = make_uint2(0u, 0u);
    else if (t < 48) padrows2[t - 32] = make_uint2(0u, 0u);
  }
}

// ---------------- local CSR: per-bucket offsets (padded x4) + adj scatter ----------------

__global__ __launch_bounds__(1024) void local_csr(
    const int* __restrict__ pairV, const int* __restrict__ pairC,
    const int* __restrict__ gcurV, const int* __restrict__ gcurC,
    int* __restrict__ off, int* __restrict__ deg, int* __restrict__ adj) {
  __shared__ int cnt[1024];
  __shared__ int s[1024];
  __shared__ int cur[1024];
  int tid = threadIdx.x;
  int b = blockIdx.x;
  const int* pairs;
  int m, obase, nn, sh, zrow;
  int* offp;
  int* degp;
  if (b < NBV) {
    pairs = pairV + (size_t)b * CAPV;
    m = gcurV[b];
    obase = b * CAPAV;
    nn = min(1024, N_VAR - (b << 10));
    sh = VSH;
    zrow = N_CONS;
    offp = off + (b << 10);
    degp = deg + (b << 10);
  } else {
    int bb = b - NBV;
    pairs = pairC + (size_t)bb * CAPC;
    m = gcurC[bb];
    obase = NBV * CAPAV + bb * CAPAC;
    nn = min(512, N_CONS - (bb << 9));
    sh = CSH;
    zrow = N_VAR;
    offp = off + N_VAR + (bb << 9);
    degp = deg + N_VAR + (bb << 9);
  }
  int mask = (1 << sh) - 1;
  cnt[tid] = 0;
  __syncthreads();
  for (int k = tid; k < m; k += 1024) atomicAdd(&cnt[pairs[k] & mask], 1);
  __syncthreads();
  int c = cnt[tid];
  int pc = (c + 3) & ~3;
  s[tid] = pc;
  __syncthreads();
  for (int d1 = 1; d1 < 1024; d1 <<= 1) {
    int x = (tid >= d1) ? s[tid - d1] : 0;
    __syncthreads();
    s[tid] += x;
    __syncthreads();
  }
  int start = obase + s[tid] - pc;
  cur[tid] = start;
  if (tid < nn) {
    offp[tid] = start;
    degp[tid] = c;
  }
  __syncthreads();
  for (int k = tid; k < m; k += 1024) {
    int pr = pairs[k];
    int p = atomicAdd(&cur[pr & mask], 1);
    adj[p] = pr >> sh;
  }
  for (int q = c; q < pc; ++q) adj[start + q] = zrow;
}

// ---------------- Fused SAGE body (MFMA dense, padded gather, 8-deep ILP) ----------------

template <int OUTBF>
__device__ __forceinline__ void sage_body(
    const uint2* __restrict__ srcbf, const uint2* __restrict__ dstbf,
    const int* __restrict__ off, const int* __restrict__ deg,
    const int* __restrict__ adj, const float* __restrict__ Wl,
    const float* __restrict__ bl, const float* __restrict__ Wr,
    float* __restrict__ outf, u16* __restrict__ outbf, int n, int v0,
    u16 (*Hs)[72], u16 (*Ws)[72], float* bls) {
  int t = threadIdx.x;
  if (t < 64) bls[t] = bl[t];

  int sn = t & 63;
  int kq = t >> 6;
  {
    unsigned pk[8];
#pragma unroll
    for (int i = 0; i < 8; ++i) {
      float w0 = Wl[(size_t)(kq * 16 + 2 * i) * 64 + sn];
      float w1 = Wl[(size_t)(kq * 16 + 2 * i + 1) * 64 + sn];
      pk[i] = pack_bf2(w0, w1);
    }
    *(uint4*)&Ws[sn][kq * 16] = make_uint4(pk[0], pk[1], pk[2], pk[3]);
    *(uint4*)&Ws[sn][kq * 16 + 8] = make_uint4(pk[4], pk[5], pk[6], pk[7]);
  }

  // gather-mean: static rows, padded x4 lists, 8-deep main + 4-deep tail
  int lane = t & 15;
  int g = t >> 4;
#pragma unroll
  for (int grp = 0; grp < 4; ++grp) {
    int r = grp * 16 + g;
    int v = v0 + r;
    float ax = 0.f, ay = 0.f, az = 0.f, aw = 0.f;
    if (v < n) {
      int s0 = off[v];
      int d = deg[v];
      int e4 = s0 + ((d + 3) & ~3);
      int i = s0;
      for (; i + 8 <= e4; i += 8) {
        int u0 = adj[i], u1 = adj[i + 1], u2 = adj[i + 2], u3 = adj[i + 3];
        int u4 = adj[i + 4], u5 = adj[i + 5], u6 = adj[i + 6], u7 = adj[i + 7];
        uint2 a0 = srcbf[(size_t)u0 * 16 + lane];
        uint2 a1 = srcbf[(size_t)u1 * 16 + lane];
        uint2 a2 = srcbf[(size_t)u2 * 16 + lane];
        uint2 a3 = srcbf[(size_t)u3 * 16 + lane];
        uint2 a4 = srcbf[(size_t)u4 * 16 + lane];
        uint2 a5 = srcbf[(size_t)u5 * 16 + lane];
        uint2 a6 = srcbf[(size_t)u6 * 16 + lane];
        uint2 a7 = srcbf[(size_t)u7 * 16 + lane];
        ax += (b2f_lo(a0.x) + b2f_lo(a1.x)) + (b2f_lo(a2.x) + b2f_lo(a3.x)) +
              (b2f_lo(a4.x) + b2f_lo(a5.x)) + (b2f_lo(a6.x) + b2f_lo(a7.x));
        ay += (b2f_hi(a0.x) + b2f_hi(a1.x)) + (b2f_hi(a2.x) + b2f_hi(a3.x)) +
              (b2f_hi(a4.x) + b2f_hi(a5.x)) + (b2f_hi(a6.x) + b2f_hi(a7.x));
        az += (b2f_lo(a0.y) + b2f_lo(a1.y)) + (b2f_lo(a2.y) + b2f_lo(a3.y)) +
              (b2f_lo(a4.y) + b2f_lo(a5.y)) + (b2f_lo(a6.y) + b2f_lo(a7.y));
        aw += (b2f_hi(a0.y) + b2f_hi(a1.y)) + (b2f_hi(a2.y) + b2f_hi(a3.y)) +
              (b2f_hi(a4.y) + b2f_hi(a5.y)) + (b2f_hi(a6.y) + b2f_hi(a7.y));
      }
      if (i < e4) {
        int u0 = adj[i], u1 = adj[i + 1], u2 = adj[i + 2], u3 = adj[i + 3];
        uint2 a0 = srcbf[(size_t)u0 * 16 + lane];
        uint2 a1 = srcbf[(size_t)u1 * 16 + lane];
        uint2 a2 = srcbf[(size_t)u2 * 16 + lane];
        uint2 a3 = srcbf[(size_t)u3 * 16 + lane];
        ax += (b2f_lo(a0.x) + b2f_lo(a1.x)) + (b2f_lo(a2.x) + b2f_lo(a3.x));
        ay += (b2f_hi(a0.x) + b2f_hi(a1.x)) + (b2f_hi(a2.x) + b2f_hi(a3.x));
        az += (b2f_lo(a0.y) + b2f_lo(a1.y)) + (b2f_lo(a2.y) + b2f_lo(a3.y));
        aw += (b2f_hi(a0.y) + b2f_hi(a1.y)) + (b2f_hi(a2.y) + b2f_hi(a3.y));
      }
      float inv = (d > 0) ? 1.f / (float)d : 0.f;
      ax *= inv;
      ay *= inv;
      az *= inv;
      aw *= inv;
    }
    *(uint2*)&Hs[r][lane * 4] = make_uint2(pack_bf2(ax, ay), pack_bf2(az, aw));
  }
  __syncthreads();

  int l = t & 63;
  int w = t >> 6;
  int m0 = w * 16;
  int rA = m0 + (l & 15);
  int koffA = (l >> 4) * 8;
  f32x4 acc[4] = {};
  {
    bf16x8 a0 = *(const bf16x8*)&Hs[rA][koffA];
    bf16x8 a1 = *(const bf16x8*)&Hs[rA][32 + koffA];
#pragma unroll
    for (int cb = 0; cb < 4; ++cb) {
      int nB = cb * 16 + (l & 15);
      bf16x8 b0 = *(const bf16x8*)&Ws[nB][koffA];
      bf16x8 b1 = *(const bf16x8*)&Ws[nB][32 + koffA];
      acc[cb] = __builtin_amdgcn_mfma_f32_16x16x32_bf16(a0, b0, acc[cb], 0, 0, 0);
      acc[cb] = __builtin_amdgcn_mfma_f32_16x16x32_bf16(a1, b1, acc[cb], 0, 0, 0);
    }
  }
  __syncthreads();

#pragma unroll
  for (int r4 = 0; r4 < 4; ++r4) {
    int idx = t + 256 * r4;
    int rowi = idx >> 4, f4 = idx & 15;
    int v = v0 + rowi;
    uint2 val = (v < n) ? dstbf[(size_t)v * 16 + f4] : make_uint2(0u, 0u);
    *(uint2*)&Hs[rowi][f4 * 4] = val;
  }
  {
    unsigned pk[8];
#pragma unroll
    for (int i = 0; i < 8; ++i) {
      float w0 = Wr[(size_t)(kq * 16 + 2 * i) * 64 + sn];
      float w1 = Wr[(size_t)(kq * 16 + 2 * i + 1) * 64 + sn];
      pk[i] = pack_bf2(w0, w1);
    }
    *(uint4*)&Ws[sn][kq * 16] = make_uint4(pk[0], pk[1], pk[2], pk[3]);
    *(uint4*)&Ws[sn][kq * 16 + 8] = make_uint4(pk[4], pk[5], pk[6], pk[7]);
  }
  __syncthreads();

  {
    bf16x8 a0 = *(const bf16x8*)&Hs[rA][koffA];
    bf16x8 a1 = *(const bf16x8*)&Hs[rA][32 + koffA];
#pragma unroll
    for (int cb = 0; cb < 4; ++cb) {
      int nB = cb * 16 + (l & 15);
      bf16x8 b0 = *(const bf16x8*)&Ws[nB][koffA];
      bf16x8 b1 = *(const bf16x8*)&Ws[nB][32 + koffA];
      acc[cb] = __builtin_amdgcn_mfma_f32_16x16x32_bf16(a0, b0, acc[cb], 0, 0, 0);
      acc[cb] = __builtin_amdgcn_mfma_f32_16x16x32_bf16(a1, b1, acc[cb], 0, 0, 0);
    }
  }

#pragma unroll
  for (int cb = 0; cb < 4; ++cb) {
    int colc = cb * 16 + (l & 15);
    float bias = bls[colc];
#pragma unroll
    for (int j = 0; j < 4; ++j) {
      int rowc = m0 + (l >> 4) * 4 + j;
      int v = v0 + rowc;
      if (v < n) {
        float val = fmaxf(acc[cb][j] + bias, 0.f);
        if (OUTBF) {
          outbf[(size_t)v * 64 + colc] = f2bf(val);
        } else {
          outf[(size_t)v * 64 + colc] = val;
        }
      }
    }
  }
}

// layer 0: both directions in one dispatch
__global__ __launch_bounds__(256) void sage_l0(
    const uint2* __restrict__ consEbf, const uint2* __restrict__ varEbf,
    const int* __restrict__ off, const int* __restrict__ deg,
    const int* __restrict__ adj, const float* __restrict__ Wl_cv,
    const float* __restrict__ bl_cv, const float* __restrict__ Wr_cv,
    const float* __restrict__ Wl_vc, const float* __restrict__ bl_vc,
    const float* __restrict__ Wr_vc, u16* __restrict__ var1bf,
    u16* __restrict__ cons1bf) {
  __shared__ u16 Hs[64][72];
  __shared__ u16 Ws[64][72];
  __shared__ float bls[64];
  int b = blockIdx.x;
  if (b < NB_VAR) {
    sage_body<1>(consEbf, varEbf, off, deg, adj, Wl_cv, bl_cv, Wr_cv, nullptr,
                 var1bf, N_VAR, b * 64, Hs, Ws, bls);
  } else {
    sage_body<1>(varEbf, consEbf, off + N_VAR, deg + N_VAR, adj, Wl_vc, bl_vc,
                 Wr_vc, nullptr, cons1bf, N_CONS, (b - NB_VAR) * 64, Hs, Ws,
                 bls);
  }
}

// layer 1: var side only, fp32 out
__global__ __launch_bounds__(256) void sage_l1(
    const uint2* __restrict__ cons1bf, const uint2* __restrict__ var1bf,
    const int* __restrict__ off, const int* __restrict__ deg,
    const int* __restrict__ adj, const float* __restrict__ Wl,
    const float* __restrict__ bl, const float* __restrict__ Wr,
    float* __restrict__ out) {
  __shared__ u16 Hs[64][72];
  __shared__ u16 Ws[64][72];
  __shared__ float bls[64];
  sage_body<0>(cons1bf, var1bf, off, deg, adj, Wl, bl, Wr, out, nullptr, N_VAR,
               blockIdx.x * 64, Hs, Ws, bls);
}

// ---------------- host ----------------

extern "C" void kernel_launch(void* const* d_in, const int* in_sizes, int n_in,
                              void* d_out, int out_size, void* d_ws, size_t ws_size,
                              hipStream_t stream) {
  const float* cons_x = (const float*)d_in[0];
  const float* var_x  = (const float*)d_in[1];
  const int*   eidx   = (const int*)d_in[2];
  const float* bi     = (const float*)d_in[4];
  const float* c_sh   = (const float*)d_in[5];
  const float* c_sc   = (const float*)d_in[6];
  const float* v_sh   = (const float*)d_in[7];
  const float* v_sc   = (const float*)d_in[8];
  const float* cW1 = (const float*)d_in[11];
  const float* cb1 = (const float*)d_in[12];
  const float* cW2 = (const float*)d_in[13];
  const float* cb2 = (const float*)d_in[14];
  const float* vW1 = (const float*)d_in[15];
  const float* vb1 = (const float*)d_in[16];
  const float* vW2 = (const float*)d_in[17];
  const float* vb2 = (const float*)d_in[18];
  const float* bW  = (const float*)d_in[19];
  const float* Wl_cv = (const float*)d_in[20];
  const float* bl_cv = (const float*)d_in[21];
  const float* Wr_cv = (const float*)d_in[22];
  const float* Wl_vc = (const float*)d_in[23];
  const float* bl_vc = (const float*)d_in[24];
  const float* Wr_vc = (const float*)d_in[25];

  const int* row = eidx;           // [E] constraint index per edge
  const int* col = eidx + N_EDGE;  // [E] variable index per edge

  char* ws = (char*)d_ws;
  size_t o = 0;
  auto alloc = [&](size_t bytes) {
    char* p = ws + o;
    o = (o + bytes + 255) & ~(size_t)255;
    return p;
  };
  int* off   = (int*)alloc((size_t)N_TOT * sizeof(int));
  int* deg   = (int*)alloc((size_t)N_TOT * sizeof(int));
  int* adj   = (int*)alloc(((size_t)NBV * CAPAV + (size_t)NBC * CAPAC) * sizeof(int));
  int* pairV = (int*)alloc((size_t)NBV * CAPV * sizeof(int));
  int* pairC = (int*)alloc((size_t)NBC * CAPC * sizeof(int));
  int* gcurV = (int*)alloc(256 * sizeof(int));
  int* gcurC = (int*)alloc(256 * sizeof(int));
  uint2* consEbf = (uint2*)alloc((size_t)(N_CONS + 1) * EMB * 2);
  uint2* varEbf  = (uint2*)alloc((size_t)(N_VAR + 1) * EMB * 2);
  uint2* cons1bf = (uint2*)alloc((size_t)(N_CONS + 1) * EMB * 2);
  uint2* var1bf  = (uint2*)alloc((size_t)N_VAR * EMB * 2);
  float* var_out = (float*)d_out;

  // bucket counters -> 0 (gcurV/gcurC are contiguous allocations)
  hipMemsetAsync(gcurV, 0, 2048, stream);

  fused_front<<<NB_SCAT + NB_CONS + NB_VAR + 1, 256, 0, stream>>>(
      row, col, gcurV, gcurC, pairV, pairC, cons_x, c_sh, c_sc, cW1, cb1, cW2,
      cb2, var_x, v_sh, v_sc, vW1, vb1, vW2, vb2, bi, bW, (u16*)consEbf,
      (u16*)varEbf, consEbf + (size_t)N_CONS * 16, varEbf + (size_t)N_VAR * 16,
      cons1bf + (size_t)N_CONS * 16);

  local_csr<<<NBV + NBC, 1024, 0, stream>>>(pairV, pairC, gcurV, gcurC, off,
                                            deg, adj);

  sage_l0<<<NB_VAR + NB_CONS, 256, 0, stream>>>(
      consEbf, varEbf, off, deg, adj, Wl_cv, bl_cv, Wr_cv, Wl_vc, bl_vc, Wr_vc,
      (u16*)var1bf, (u16*)cons1bf);
  sage_l1<<<NB_VAR, 256, 0, stream>>>(cons1bf, var1bf, off, deg, adj,
                                      Wl_cv + 4096, bl_cv + 64, Wr_cv + 4096,
                                      var_out);
}

// Round 13
// 244.246 us; speedup vs baseline: 1.0325x; 1.0325x over previous
//
#include <hip/hip_runtime.h>

#define N_CONS 100000
#define N_VAR  200000
#define N_TOT  (N_CONS + N_VAR)
#define N_EDGE 2000000
#define EMB 64

#define VSH 10
#define NBV 196    // ceil(200000/1024)
#define CAPV 12288
#define CSH 9
#define NBC 196    // ceil(100000/512)
#define CAPC 12288
#define CAPAV (CAPV + 3 * 1024)  // padded adj capacity per var bucket
#define CAPAC (CAPC + 3 * 512)   // padded adj capacity per cons bucket
#define NB_VAR ((N_VAR + 63) / 64)    // 3125
#define NB_CONS ((N_CONS + 63) / 64)  // 1563
#define NB_SCAT 512

typedef unsigned short u16;
typedef __attribute__((ext_vector_type(8))) short bf16x8;
typedef __attribute__((ext_vector_type(4))) float f32x4;

// ---------------- bf16 helpers ----------------

__device__ __forceinline__ float b2f_lo(unsigned u) {
  union { unsigned i; float f; } c;
  c.i = u << 16;
  return c.f;
}
__device__ __forceinline__ float b2f_hi(unsigned u) {
  union { unsigned i; float f; } c;
  c.i = u & 0xFFFF0000u;
  return c.f;
}
__device__ __forceinline__ unsigned pack_bf2(float a, float b) {
  unsigned ua = __float_as_uint(a), ub = __float_as_uint(b);
  unsigned ra = (ua + 0x7FFFu + ((ua >> 16) & 1u)) >> 16;
  unsigned rb = (ub + 0x7FFFu + ((ub >> 16) & 1u)) >> 16;
  return ra | (rb << 16);
}
__device__ __forceinline__ u16 f2bf(float a) {
  unsigned ua = __float_as_uint(a);
  return (u16)((ua + 0x7FFFu + ((ua >> 16) & 1u)) >> 16);
}

// ---------------- fused front: bucket_scatter + embed(x2) + pad-row zero ----------------

__device__ __forceinline__ void scatter_body(
    int b, char* smem, const int* __restrict__ row, const int* __restrict__ col,
    int* __restrict__ gcurV, int* __restrict__ gcurC, int* __restrict__ pairV,
    int* __restrict__ pairC) {
  int* hV = (int*)smem;
  int* hC = hV + NBV;
  int tid = threadIdx.x;
  int chunk = (N_EDGE + NB_SCAT - 1) / NB_SCAT;
  int lo = b * chunk;
  int hi = min(N_EDGE, lo + chunk);
  for (int i = tid; i < NBV; i += 256) hV[i] = 0;
  for (int i = tid; i < NBC; i += 256) hC[i] = 0;
  __syncthreads();
  for (int e = lo + tid; e < hi; e += 256) {
    atomicAdd(&hV[col[e] >> VSH], 1);
    atomicAdd(&hC[row[e] >> CSH], 1);
  }
  __syncthreads();
  for (int i = tid; i < NBV; i += 256) {
    int c = hV[i];
    hV[i] = c ? (i * CAPV + atomicAdd(&gcurV[i], c)) : 0;
  }
  for (int i = tid; i < NBC; i += 256) {
    int c = hC[i];
    hC[i] = c ? (i * CAPC + atomicAdd(&gcurC[i], c)) : 0;
  }
  __syncthreads();
  for (int e = lo + tid; e < hi; e += 256) {
    int r = row[e], c = col[e];
    int p = atomicAdd(&hV[c >> VSH], 1);
    pairV[p] = (r << VSH) | (c & ((1 << VSH) - 1));
    int q = atomicAdd(&hC[r >> CSH], 1);
    pairC[q] = (c << CSH) | (r & ((1 << CSH) - 1));
  }
}

// Embedding: GEMM1 fp32 (K=F), GEMM2 on MFMA (K=64, bf16)
template <int F>
__device__ __forceinline__ void embed_body(
    int blk, char* smem, const float* __restrict__ x,
    const float* __restrict__ shift, const float* __restrict__ scale,
    const float* __restrict__ W1, const float* __restrict__ b1,
    const float* __restrict__ W2, const float* __restrict__ b2,
    const float* __restrict__ bi, const float* __restrict__ bW,
    u16* __restrict__ outbf, int n) {
  float* Xs = (float*)smem;                    // [F][68]
  float* W1s = Xs + F * 68;                    // [F][68]
  u16 (*Hs)[72] = (u16(*)[72])(W1s + F * 68);  // [64][72]
  u16 (*W2s)[72] = (u16(*)[72])((char*)Hs + 64 * 72 * 2);
  float* b1s = (float*)((char*)W2s + 64 * 72 * 2);
  float* b2s = b1s + 64;
  float* bWs = b2s + 64;
  float* bis = bWs + 64;
  int t = threadIdx.x;
  int v0 = blk * 64;

  int sn = t & 63;
  int kq = t >> 6;
  {
    unsigned pk[8];
#pragma unroll
    for (int i = 0; i < 8; ++i) {
      float w0 = W2[(size_t)(kq * 16 + 2 * i) * 64 + sn];
      float w1 = W2[(size_t)(kq * 16 + 2 * i + 1) * 64 + sn];
      pk[i] = pack_bf2(w0, w1);
    }
    *(uint4*)&W2s[sn][kq * 16] = make_uint4(pk[0], pk[1], pk[2], pk[3]);
    *(uint4*)&W2s[sn][kq * 16 + 8] = make_uint4(pk[4], pk[5], pk[6], pk[7]);
  }
  for (int i = t; i < F * 64; i += 256) {
    int k = i >> 6, j = i & 63;
    W1s[k * 68 + j] = W1[i] * scale[k];
  }
  if (t < 64) {
    float acc = b1[t];
#pragma unroll
    for (int k = 0; k < F; ++k) acc += shift[k] * scale[k] * W1[k * 64 + t];
    b1s[t] = acc;
    b2s[t] = b2[t];
    bWs[t] = bW ? bW[t] : 0.f;
    bis[t] = (bi && v0 + t < n) ? bi[v0 + t] : 0.f;
  }
  for (int i = t; i < 64 * F; i += 256) {
    int r = i / F, k = i - r * F;
    int v = v0 + r;
    Xs[k * 68 + r] = (v < n) ? x[(size_t)v * F + k] : 0.f;
  }
  __syncthreads();

  int jt = t & 15;
  int vt = t >> 4;
  float c[4][4] = {};
#pragma unroll
  for (int k = 0; k < F; ++k) {
    float4 xv = *(const float4*)&Xs[k * 68 + vt * 4];
    float4 wv = *(const float4*)&W1s[k * 68 + jt * 4];
    c[0][0] += xv.x * wv.x; c[0][1] += xv.x * wv.y; c[0][2] += xv.x * wv.z; c[0][3] += xv.x * wv.w;
    c[1][0] += xv.y * wv.x; c[1][1] += xv.y * wv.y; c[1][2] += xv.y * wv.z; c[1][3] += xv.y * wv.w;
    c[2][0] += xv.z * wv.x; c[2][1] += xv.z * wv.y; c[2][2] += xv.z * wv.z; c[2][3] += xv.z * wv.w;
    c[3][0] += xv.w * wv.x; c[3][1] += xv.w * wv.y; c[3][2] += xv.w * wv.z; c[3][3] += xv.w * wv.w;
  }
#pragma unroll
  for (int i = 0; i < 4; ++i) {
    float h0 = fmaxf(c[i][0] + b1s[jt * 4 + 0], 0.f);
    float h1 = fmaxf(c[i][1] + b1s[jt * 4 + 1], 0.f);
    float h2 = fmaxf(c[i][2] + b1s[jt * 4 + 2], 0.f);
    float h3 = fmaxf(c[i][3] + b1s[jt * 4 + 3], 0.f);
    *(uint2*)&Hs[vt * 4 + i][jt * 4] = make_uint2(pack_bf2(h0, h1), pack_bf2(h2, h3));
  }
  __syncthreads();

  int l = t & 63;
  int w = t >> 6;
  int m0 = w * 16;
  int rA = m0 + (l & 15);
  int koffA = (l >> 4) * 8;
  f32x4 acc[4] = {};
  {
    bf16x8 a0 = *(const bf16x8*)&Hs[rA][koffA];
    bf16x8 a1 = *(const bf16x8*)&Hs[rA][32 + koffA];
#pragma unroll
    for (int cb = 0; cb < 4; ++cb) {
      int nB = cb * 16 + (l & 15);
      bf16x8 b0 = *(const bf16x8*)&W2s[nB][koffA];
      bf16x8 bb1 = *(const bf16x8*)&W2s[nB][32 + koffA];
      acc[cb] = __builtin_amdgcn_mfma_f32_16x16x32_bf16(a0, b0, acc[cb], 0, 0, 0);
      acc[cb] = __builtin_amdgcn_mfma_f32_16x16x32_bf16(a1, bb1, acc[cb], 0, 0, 0);
    }
  }
#pragma unroll
  for (int cb = 0; cb < 4; ++cb) {
    int colc = cb * 16 + (l & 15);
    float bias = b2s[colc];
    float bwv = bWs[colc];
#pragma unroll
    for (int j = 0; j < 4; ++j) {
      int rowc = m0 + (l >> 4) * 4 + j;
      int v = v0 + rowc;
      if (v < n) {
        float val = fmaxf(acc[cb][j] + bias, 0.f) + bis[rowc] * bwv;
        outbf[(size_t)v * 64 + colc] = f2bf(val);
      }
    }
  }
}

#define FRONT_SMEM 29824

__global__ __launch_bounds__(256) void fused_front(
    const int* __restrict__ row, const int* __restrict__ col,
    int* __restrict__ gcurV, int* __restrict__ gcurC, int* __restrict__ pairV,
    int* __restrict__ pairC, const float* __restrict__ cons_x,
    const float* __restrict__ c_sh, const float* __restrict__ c_sc,
    const float* __restrict__ cW1, const float* __restrict__ cb1,
    const float* __restrict__ cW2, const float* __restrict__ cb2,
    const float* __restrict__ var_x, const float* __restrict__ v_sh,
    const float* __restrict__ v_sc, const float* __restrict__ vW1,
    const float* __restrict__ vb1, const float* __restrict__ vW2,
    const float* __restrict__ vb2, const float* __restrict__ bi,
    const float* __restrict__ bW, u16* __restrict__ consEbf,
    u16* __restrict__ varEbf, uint2* __restrict__ padrows0,
    uint2* __restrict__ padrows1, uint2* __restrict__ padrows2) {
  __shared__ __align__(16) char smem[FRONT_SMEM];
  int b = blockIdx.x;
  if (b < NB_SCAT) {
    scatter_body(b, smem, row, col, gcurV, gcurC, pairV, pairC);
  } else if (b < NB_SCAT + NB_CONS) {
    embed_body<5>(b - NB_SCAT, smem, cons_x, c_sh, c_sc, cW1, cb1, cW2, cb2,
                  nullptr, nullptr, consEbf, N_CONS);
  } else if (b < NB_SCAT + NB_CONS + NB_VAR) {
    embed_body<19>(b - NB_SCAT - NB_CONS, smem, var_x, v_sh, v_sc, vW1, vb1,
                   vW2, vb2, bi, bW, varEbf, N_VAR);
  } else {
    int t = threadIdx.x;
    if (t < 16) padrows0[t] = make_uint2(0u, 0u);
    else if (t < 32) padrows1[t - 16] = make_uint2(0u, 0u);
    else if (t < 48) padrows2[t - 32] = make_uint2(0u, 0u);
  }
}

// ---------------- local CSR: per-bucket offsets (padded x4) + adj scatter ----------------

__global__ __launch_bounds__(1024) void local_csr(
    const int* __restrict__ pairV, const int* __restrict__ pairC,
    const int* __restrict__ gcurV, const int* __restrict__ gcurC,
    int* __restrict__ off, int* __restrict__ deg, int* __restrict__ adj) {
  __shared__ int cnt[1024];
  __shared__ int s[1024];
  __shared__ int cur[1024];
  int tid = threadIdx.x;
  int b = blockIdx.x;
  const int* pairs;
  int m, obase, nn, sh, zrow;
  int* offp;
  int* degp;
  if (b < NBV) {
    pairs = pairV + (size_t)b * CAPV;
    m = gcurV[b];
    obase = b * CAPAV;
    nn = min(1024, N_VAR - (b << 10));
    sh = VSH;
    zrow = N_CONS;
    offp = off + (b << 10);
    degp = deg + (b << 10);
  } else {
    int bb = b - NBV;
    pairs = pairC + (size_t)bb * CAPC;
    m = gcurC[bb];
    obase = NBV * CAPAV + bb * CAPAC;
    nn = min(512, N_CONS - (bb << 9));
    sh = CSH;
    zrow = N_VAR;
    offp = off + N_VAR + (bb << 9);
    degp = deg + N_VAR + (bb << 9);
  }
  int mask = (1 << sh) - 1;
  cnt[tid] = 0;
  __syncthreads();
  for (int k = tid; k < m; k += 1024) atomicAdd(&cnt[pairs[k] & mask], 1);
  __syncthreads();
  int c = cnt[tid];
  int pc = (c + 3) & ~3;
  s[tid] = pc;
  __syncthreads();
  for (int d1 = 1; d1 < 1024; d1 <<= 1) {
    int x = (tid >= d1) ? s[tid - d1] : 0;
    __syncthreads();
    s[tid] += x;
    __syncthreads();
  }
  int start = obase + s[tid] - pc;
  cur[tid] = start;
  if (tid < nn) {
    offp[tid] = start;
    degp[tid] = c;
  }
  __syncthreads();
  for (int k = tid; k < m; k += 1024) {
    int pr = pairs[k];
    int p = atomicAdd(&cur[pr & mask], 1);
    adj[p] = pr >> sh;
  }
  for (int q = c; q < pc; ++q) adj[start + q] = zrow;
}

// ---------------- Fused SAGE body (MFMA dense, padded 4-deep static gather) ----------------

template <int OUTBF>
__device__ __forceinline__ void sage_body(
    const uint2* __restrict__ srcbf, const uint2* __restrict__ dstbf,
    const int* __restrict__ off, const int* __restrict__ deg,
    const int* __restrict__ adj, const float* __restrict__ Wl,
    const float* __restrict__ bl, const float* __restrict__ Wr,
    float* __restrict__ outf, u16* __restrict__ outbf, int n, int v0,
    u16 (*Hs)[72], u16 (*Ws)[72], float* bls) {
  int t = threadIdx.x;
  if (t < 64) bls[t] = bl[t];

  int sn = t & 63;
  int kq = t >> 6;
  {
    unsigned pk[8];
#pragma unroll
    for (int i = 0; i < 8; ++i) {
      float w0 = Wl[(size_t)(kq * 16 + 2 * i) * 64 + sn];
      float w1 = Wl[(size_t)(kq * 16 + 2 * i + 1) * 64 + sn];
      pk[i] = pack_bf2(w0, w1);
    }
    *(uint4*)&Ws[sn][kq * 16] = make_uint4(pk[0], pk[1], pk[2], pk[3]);
    *(uint4*)&Ws[sn][kq * 16 + 8] = make_uint4(pk[4], pk[5], pk[6], pk[7]);
  }

  // gather-mean: static rows, padded x4 lists, uniform 4-deep loop
  int lane = t & 15;
  int g = t >> 4;
#pragma unroll
  for (int grp = 0; grp < 4; ++grp) {
    int r = grp * 16 + g;
    int v = v0 + r;
    float ax = 0.f, ay = 0.f, az = 0.f, aw = 0.f;
    if (v < n) {
      int s0 = off[v];
      int d = deg[v];
      int e4 = s0 + ((d + 3) & ~3);
      for (int i = s0; i < e4; i += 4) {
        int u0 = adj[i], u1 = adj[i + 1], u2 = adj[i + 2], u3 = adj[i + 3];
        uint2 a0 = srcbf[(size_t)u0 * 16 + lane];
        uint2 a1 = srcbf[(size_t)u1 * 16 + lane];
        uint2 a2 = srcbf[(size_t)u2 * 16 + lane];
        uint2 a3 = srcbf[(size_t)u3 * 16 + lane];
        ax += (b2f_lo(a0.x) + b2f_lo(a1.x)) + (b2f_lo(a2.x) + b2f_lo(a3.x));
        ay += (b2f_hi(a0.x) + b2f_hi(a1.x)) + (b2f_hi(a2.x) + b2f_hi(a3.x));
        az += (b2f_lo(a0.y) + b2f_lo(a1.y)) + (b2f_lo(a2.y) + b2f_lo(a3.y));
        aw += (b2f_hi(a0.y) + b2f_hi(a1.y)) + (b2f_hi(a2.y) + b2f_hi(a3.y));
      }
      float inv = (d > 0) ? 1.f / (float)d : 0.f;
      ax *= inv;
      ay *= inv;
      az *= inv;
      aw *= inv;
    }
    *(uint2*)&Hs[r][lane * 4] = make_uint2(pack_bf2(ax, ay), pack_bf2(az, aw));
  }
  __syncthreads();

  int l = t & 63;
  int w = t >> 6;
  int m0 = w * 16;
  int rA = m0 + (l & 15);
  int koffA = (l >> 4) * 8;
  f32x4 acc[4] = {};
  {
    bf16x8 a0 = *(const bf16x8*)&Hs[rA][koffA];
    bf16x8 a1 = *(const bf16x8*)&Hs[rA][32 + koffA];
#pragma unroll
    for (int cb = 0; cb < 4; ++cb) {
      int nB = cb * 16 + (l & 15);
      bf16x8 b0 = *(const bf16x8*)&Ws[nB][koffA];
      bf16x8 b1 = *(const bf16x8*)&Ws[nB][32 + koffA];
      acc[cb] = __builtin_amdgcn_mfma_f32_16x16x32_bf16(a0, b0, acc[cb], 0, 0, 0);
      acc[cb] = __builtin_amdgcn_mfma_f32_16x16x32_bf16(a1, b1, acc[cb], 0, 0, 0);
    }
  }
  __syncthreads();

#pragma unroll
  for (int r4 = 0; r4 < 4; ++r4) {
    int idx = t + 256 * r4;
    int rowi = idx >> 4, f4 = idx & 15;
    int v = v0 + rowi;
    uint2 val = (v < n) ? dstbf[(size_t)v * 16 + f4] : make_uint2(0u, 0u);
    *(uint2*)&Hs[rowi][f4 * 4] = val;
  }
  {
    unsigned pk[8];
#pragma unroll
    for (int i = 0; i < 8; ++i) {
      float w0 = Wr[(size_t)(kq * 16 + 2 * i) * 64 + sn];
      float w1 = Wr[(size_t)(kq * 16 + 2 * i + 1) * 64 + sn];
      pk[i] = pack_bf2(w0, w1);
    }
    *(uint4*)&Ws[sn][kq * 16] = make_uint4(pk[0], pk[1], pk[2], pk[3]);
    *(uint4*)&Ws[sn][kq * 16 + 8] = make_uint4(pk[4], pk[5], pk[6], pk[7]);
  }
  __syncthreads();

  {
    bf16x8 a0 = *(const bf16x8*)&Hs[rA][koffA];
    bf16x8 a1 = *(const bf16x8*)&Hs[rA][32 + koffA];
#pragma unroll
    for (int cb = 0; cb < 4; ++cb) {
      int nB = cb * 16 + (l & 15);
      bf16x8 b0 = *(const bf16x8*)&Ws[nB][koffA];
      bf16x8 b1 = *(const bf16x8*)&Ws[nB][32 + koffA];
      acc[cb] = __builtin_amdgcn_mfma_f32_16x16x32_bf16(a0, b0, acc[cb], 0, 0, 0);
      acc[cb] = __builtin_amdgcn_mfma_f32_16x16x32_bf16(a1, b1, acc[cb], 0, 0, 0);
    }
  }

#pragma unroll
  for (int cb = 0; cb < 4; ++cb) {
    int colc = cb * 16 + (l & 15);
    float bias = bls[colc];
#pragma unroll
    for (int j = 0; j < 4; ++j) {
      int rowc = m0 + (l >> 4) * 4 + j;
      int v = v0 + rowc;
      if (v < n) {
        float val = fmaxf(acc[cb][j] + bias, 0.f);
        if (OUTBF) {
          outbf[(size_t)v * 64 + colc] = f2bf(val);
        } else {
          outf[(size_t)v * 64 + colc] = val;
        }
      }
    }
  }
}

// layer 0: both directions in one dispatch
__global__ __launch_bounds__(256) void sage_l0(
    const uint2* __restrict__ consEbf, const uint2* __restrict__ varEbf,
    const int* __restrict__ off, const int* __restrict__ deg,
    const int* __restrict__ adj, const float* __restrict__ Wl_cv,
    const float* __restrict__ bl_cv, const float* __restrict__ Wr_cv,
    const float* __restrict__ Wl_vc, const float* __restrict__ bl_vc,
    const float* __restrict__ Wr_vc, u16* __restrict__ var1bf,
    u16* __restrict__ cons1bf) {
  __shared__ u16 Hs[64][72];
  __shared__ u16 Ws[64][72];
  __shared__ float bls[64];
  int b = blockIdx.x;
  if (b < NB_VAR) {
    sage_body<1>(consEbf, varEbf, off, deg, adj, Wl_cv, bl_cv, Wr_cv, nullptr,
                 var1bf, N_VAR, b * 64, Hs, Ws, bls);
  } else {
    sage_body<1>(varEbf, consEbf, off + N_VAR, deg + N_VAR, adj, Wl_vc, bl_vc,
                 Wr_vc, nullptr, cons1bf, N_CONS, (b - NB_VAR) * 64, Hs, Ws,
                 bls);
  }
}

// layer 1: var side only, fp32 out
__global__ __launch_bounds__(256) void sage_l1(
    const uint2* __restrict__ cons1bf, const uint2* __restrict__ var1bf,
    const int* __restrict__ off, const int* __restrict__ deg,
    const int* __restrict__ adj, const float* __restrict__ Wl,
    const float* __restrict__ bl, const float* __restrict__ Wr,
    float* __restrict__ out) {
  __shared__ u16 Hs[64][72];
  __shared__ u16 Ws[64][72];
  __shared__ float bls[64];
  sage_body<0>(cons1bf, var1bf, off, deg, adj, Wl, bl, Wr, out, nullptr, N_VAR,
               blockIdx.x * 64, Hs, Ws, bls);
}

// ---------------- host ----------------

extern "C" void kernel_launch(void* const* d_in, const int* in_sizes, int n_in,
                              void* d_out, int out_size, void* d_ws, size_t ws_size,
                              hipStream_t stream) {
  const float* cons_x = (const float*)d_in[0];
  const float* var_x  = (const float*)d_in[1];
  const int*   eidx   = (const int*)d_in[2];
  const float* bi     = (const float*)d_in[4];
  const float* c_sh   = (const float*)d_in[5];
  const float* c_sc   = (const float*)d_in[6];
  const float* v_sh   = (const float*)d_in[7];
  const float* v_sc   = (const float*)d_in[8];
  const float* cW1 = (const float*)d_in[11];
  const float* cb1 = (const float*)d_in[12];
  const float* cW2 = (const float*)d_in[13];
  const float* cb2 = (const float*)d_in[14];
  const float* vW1 = (const float*)d_in[15];
  const float* vb1 = (const float*)d_in[16];
  const float* vW2 = (const float*)d_in[17];
  const float* vb2 = (const float*)d_in[18];
  const float* bW  = (const float*)d_in[19];
  const float* Wl_cv = (const float*)d_in[20];
  const float* bl_cv = (const float*)d_in[21];
  const float* Wr_cv = (const float*)d_in[22];
  const float* Wl_vc = (const float*)d_in[23];
  const float* bl_vc = (const float*)d_in[24];
  const float* Wr_vc = (const float*)d_in[25];

  const int* row = eidx;           // [E] constraint index per edge
  const int* col = eidx + N_EDGE;  // [E] variable index per edge

  char* ws = (char*)d_ws;
  size_t o = 0;
  auto alloc = [&](size_t bytes) {
    char* p = ws + o;
    o = (o + bytes + 255) & ~(size_t)255;
    return p;
  };
  int* off   = (int*)alloc((size_t)N_TOT * sizeof(int));
  int* deg   = (int*)alloc((size_t)N_TOT * sizeof(int));
  int* adj   = (int*)alloc(((size_t)NBV * CAPAV + (size_t)NBC * CAPAC) * sizeof(int));
  int* pairV = (int*)alloc((size_t)NBV * CAPV * sizeof(int));
  int* pairC = (int*)alloc((size_t)NBC * CAPC * sizeof(int));
  int* gcurV = (int*)alloc(256 * sizeof(int));
  int* gcurC = (int*)alloc(256 * sizeof(int));
  uint2* consEbf = (uint2*)alloc((size_t)(N_CONS + 1) * EMB * 2);
  uint2* varEbf  = (uint2*)alloc((size_t)(N_VAR + 1) * EMB * 2);
  uint2* cons1bf = (uint2*)alloc((size_t)(N_CONS + 1) * EMB * 2);
  uint2* var1bf  = (uint2*)alloc((size_t)N_VAR * EMB * 2);
  float* var_out = (float*)d_out;

  // bucket counters -> 0 (gcurV/gcurC are contiguous allocations)
  hipMemsetAsync(gcurV, 0, 2048, stream);

  fused_front<<<NB_SCAT + NB_CONS + NB_VAR + 1, 256, 0, stream>>>(
      row, col, gcurV, gcurC, pairV, pairC, cons_x, c_sh, c_sc, cW1, cb1, cW2,
      cb2, var_x, v_sh, v_sc, vW1, vb1, vW2, vb2, bi, bW, (u16*)consEbf,
      (u16*)varEbf, consEbf + (size_t)N_CONS * 16, varEbf + (size_t)N_VAR * 16,
      cons1bf + (size_t)N_CONS * 16);

  local_csr<<<NBV + NBC, 1024, 0, stream>>>(pairV, pairC, gcurV, gcurC, off,
                                            deg, adj);

  sage_l0<<<NB_VAR + NB_CONS, 256, 0, stream>>>(
      consEbf, varEbf, off, deg, adj, Wl_cv, bl_cv, Wr_cv, Wl_vc, bl_vc, Wr_vc,
      (u16*)var1bf, (u16*)cons1bf);
  sage_l1<<<NB_VAR, 256, 0, stream>>>(cons1bf, var1bf, off, deg, adj,
                                      Wl_cv + 4096, bl_cv + 64, Wr_cv + 4096,
                                      var_out);
}